// Round 1
// baseline (3246.305 us; speedup 1.0000x reference)
//
#include <hip/hip_runtime.h>
#include <math.h>

#define B_   4
#define N_   6
#define CIN  512
#define CT   64
#define Dd   41
#define FH   16
#define FW   44
#define NPIX (FH*FW)      // 704
#define NO   (Dd+CT)      // 105
#define NXX  128
#define NYY  128
#define NZZ  1
#define TOT  (B_*NZZ*NYY*NXX)   // 65536

#define PIXT 32
#define NTILE (NPIX/PIXT) // 22
#define KC   32

// ---------------- helpers ----------------

__device__ __forceinline__ void inv3(const double* m, double* o) {
    double a=m[0],b=m[1],c=m[2],d=m[3],e=m[4],f=m[5],g=m[6],h=m[7],i=m[8];
    double A  =  (e*i - f*h);
    double Bc = -(d*i - f*g);
    double Cc =  (d*h - e*g);
    double det = a*A + b*Bc + c*Cc;
    double inv = 1.0/det;
    o[0]=A*inv;            o[1]=-(b*i - c*h)*inv;  o[2]= (b*f - c*e)*inv;
    o[3]=Bc*inv;           o[4]= (a*i - c*g)*inv;  o[5]=-(a*f - c*d)*inv;
    o[6]=Cc*inv;           o[7]=-(a*h - b*g)*inv;  o[8]= (a*e - b*d)*inv;
}

__device__ __forceinline__ void atomAddF(float* p, float v) {
    unsafeAtomicAdd(p, v);   // global_atomic_add_f32, device scope
}

// ---------------- kernel A: per-(b,n) transforms (double) ----------------
// tf layout per bn (24 doubles): [0..8]=comb=R@inv(K), [9..17]=inv(post_rots),
// [18..20]=trans, [21..23]=post_trans
__global__ void tf_kernel(const float* __restrict__ rots,
                          const float* __restrict__ trans,
                          const float* __restrict__ intrins,
                          const float* __restrict__ post_rots,
                          const float* __restrict__ post_trans,
                          double* __restrict__ tf) {
    int bn = threadIdx.x;
    if (bn >= B_*N_) return;
    double k[9], pr[9], r[9], ik[9], ipr[9], c[9];
    for (int i=0;i<9;i++) { k[i]=intrins[bn*9+i]; pr[i]=post_rots[bn*9+i]; r[i]=rots[bn*9+i]; }
    inv3(k, ik);
    inv3(pr, ipr);
    for (int i=0;i<3;i++)
        for (int j=0;j<3;j++) {
            double s = 0.0;
            for (int kk=0;kk<3;kk++) s += r[i*3+kk]*ik[kk*3+j];
            c[i*3+j] = s;
        }
    double* o = tf + bn*24;
    for (int i=0;i<9;i++) o[i]   = c[i];
    for (int i=0;i<9;i++) o[9+i] = ipr[i];
    for (int i=0;i<3;i++) o[18+i] = (double)trans[bn*3+i];
    for (int i=0;i<3;i++) o[21+i] = (double)post_trans[bn*3+i];
}

// ---------------- kernel B: fused GEMM + softmax + geometry + scatter ----------------
__global__ __launch_bounds__(256) void fused_kernel(
    const float* __restrict__ x, const float* __restrict__ Wd,
    const float* __restrict__ bd, const double* __restrict__ tf,
    float* __restrict__ scat)
{
    __shared__ float  s_x[KC*PIXT];       // 32x32  = 4 KB
    __shared__ float  s_w[KC*128];        // 32x128 = 16 KB (o permuted: [k][q*16+j], o=q+8j)
    __shared__ float  s_feat[NO*PIXT];    // 105x32 = 13.4 KB
    __shared__ float  s_red[8*PIXT];
    __shared__ float  s_max[PIXT];
    __shared__ float  s_inv[PIXT];
    __shared__ int    s_vox[Dd*PIXT];     // 41x32
    __shared__ double s_tf[24];

    const int t    = threadIdx.x;
    const int p    = t & (PIXT-1);
    const int q    = t >> 5;             // 0..7
    const int bn   = blockIdx.x / NTILE;
    const int tile = blockIdx.x % NTILE;
    const int pix0 = tile * PIXT;
    const int b    = bn / N_;

    if (t < 24) s_tf[t] = tf[bn*24 + t];
    for (int i=t; i<KC*128; i+=256) s_w[i] = 0.0f;   // zero pads once
    __syncthreads();

    float acc[16];
    #pragma unroll
    for (int j=0;j<16;j++) acc[j] = 0.0f;

    const float* xbn = x + (size_t)bn * CIN * NPIX + pix0;

    for (int k0 = 0; k0 < CIN; k0 += KC) {
        // stage x tile: 32k x 32p, one float4 per thread
        {
            int kk  = t >> 3;
            int pp4 = (t & 7) * 4;
            float4 v = *(const float4*)&xbn[(size_t)(k0+kk)*NPIX + pp4];
            *(float4*)&s_x[kk*PIXT + pp4] = v;
        }
        // stage Wd tile: 105o x 32k, permuted store
        for (int idx4 = t; idx4 < (NO*KC)/4; idx4 += 256) {   // 840
            int o  = idx4 >> 3;
            int kk = (idx4 & 7) * 4;
            float4 v = *(const float4*)&Wd[o*CIN + k0 + kk];
            int off = ((o & 7) << 4) + (o >> 3);
            s_w[(kk+0)*128 + off] = v.x;
            s_w[(kk+1)*128 + off] = v.y;
            s_w[(kk+2)*128 + off] = v.z;
            s_w[(kk+3)*128 + off] = v.w;
        }
        __syncthreads();

        #pragma unroll
        for (int kk = 0; kk < KC; kk++) {
            float xv = s_x[kk*PIXT + p];
            const float4* wrow = (const float4*)&s_w[kk*128 + q*16];
            #pragma unroll
            for (int jj = 0; jj < 4; jj++) {
                float4 wv = wrow[jj];
                acc[jj*4+0] += wv.x * xv;
                acc[jj*4+1] += wv.y * xv;
                acc[jj*4+2] += wv.z * xv;
                acc[jj*4+3] += wv.w * xv;
            }
        }
        __syncthreads();
    }

    // write feat (+bias) to LDS
    #pragma unroll
    for (int j=0;j<16;j++) {
        int o = q + 8*j;
        if (o < NO) s_feat[o*PIXT + p] = acc[j] + bd[o];
    }
    __syncthreads();

    // ---- softmax over depth rows 0..40 ----
    float m = -3.0e38f;
    for (int d=q; d<Dd; d+=8) m = fmaxf(m, s_feat[d*PIXT+p]);
    s_red[q*PIXT+p] = m;
    __syncthreads();
    if (q == 0) {
        float mm = s_red[p];
        #pragma unroll
        for (int i=1;i<8;i++) mm = fmaxf(mm, s_red[i*PIXT+p]);
        s_max[p] = mm;
    }
    __syncthreads();
    {
        float mm = s_max[p];
        float ssum = 0.0f;
        for (int d=q; d<Dd; d+=8) {
            float e = expf(s_feat[d*PIXT+p] - mm);
            s_feat[d*PIXT+p] = e;
            ssum += e;
        }
        s_red[q*PIXT+p] = ssum;
    }
    __syncthreads();
    if (q == 0) {
        float s = 0.0f;
        #pragma unroll
        for (int i=0;i<8;i++) s += s_red[i*PIXT+p];
        s_inv[p] = 1.0f / s;
    }
    __syncthreads();

    // ---- geometry: per (d,p) voxel index (double, matches np-f64 ref) ----
    const double DXD = (double)0.8f;                  // 0.800000011920928955
    const double LOX = (double)(-50.8f) - DXD*0.5;
    const double LOY = LOX;
    const double DZD = 20.0;
    const double LOZ = -10.0;

    for (int id = t; id < Dd*PIXT; id += 256) {
        int d  = id >> 5;
        int pp = id & (PIXT-1);
        int pixg = pix0 + pp;
        int hh = pixg / FW, ww = pixg % FW;
        double fx = (double)((float)(ww * (703.0/43.0)));   // linspace f64->f32->f64
        double fy = (double)((float)(hh * 17.0));
        double fz = 4.0 + (double)d;
        double px = fx - s_tf[21], py = fy - s_tf[22], pz = fz - s_tf[23];
        double qx = s_tf[ 9]*px + s_tf[10]*py + s_tf[11]*pz;
        double qy = s_tf[12]*px + s_tf[13]*py + s_tf[14]*pz;
        double qz = s_tf[15]*px + s_tf[16]*py + s_tf[17]*pz;
        double rx = qx*qz, ry = qy*qz, rz = qz;
        double sx = s_tf[0]*rx + s_tf[1]*ry + s_tf[2]*rz + s_tf[18];
        double sy = s_tf[3]*rx + s_tf[4]*ry + s_tf[5]*rz + s_tf[19];
        double sz = s_tf[6]*rx + s_tf[7]*ry + s_tf[8]*rz + s_tf[20];
        int gx = (int)((sx - LOX) / DXD);   // trunc toward zero == astype(int32)
        int gy = (int)((sy - LOY) / DXD);
        int gz = (int)((sz - LOZ) / DZD);
        bool kept = (gx>=0) & (gx<NXX) & (gy>=0) & (gy<NYY) & (gz>=0) & (gz<NZZ);
        s_vox[id] = kept ? (((b*NZZ + gz)*NYY + gy)*NXX + gx) : -1;
    }
    __syncthreads();

    // ---- scatter: thread (p,q) handles pixel p, channels q*8..q*8+7 ----
    for (int d = 0; d < Dd; d++) {
        int vox = s_vox[d*PIXT + p];
        if (vox >= 0) {
            float w = s_feat[d*PIXT + p] * s_inv[p];
            float* dst = scat + (size_t)vox*CT + q*8;
            #pragma unroll
            for (int i=0;i<8;i++) {
                atomAddF(dst + i, w * s_feat[(Dd + q*8 + i)*PIXT + p]);
            }
        }
    }
}

// ---------------- kernel C: transpose (b,pix,ct) -> (b,ct,pix) ----------------
__global__ __launch_bounds__(256) void transpose_k(const float* __restrict__ scat,
                                                   float* __restrict__ out) {
    __shared__ float tile[64][65];
    int b  = blockIdx.x >> 8;
    int t0 = (blockIdx.x & 255) * 64;
    const float* src = scat + (size_t)b * (NYY*NXX) * CT;
    #pragma unroll
    for (int i=0;i<16;i++) {
        int idx = threadIdx.x + i*256;
        int p = idx >> 6, c = idx & 63;
        tile[p][c] = src[(size_t)(t0+p)*CT + c];
    }
    __syncthreads();
    float* dst = out + (size_t)b * CT * (NYY*NXX);
    #pragma unroll
    for (int i=0;i<16;i++) {
        int idx = threadIdx.x + i*256;
        int c = idx >> 6, p = idx & 63;
        dst[(size_t)c*(NYY*NXX) + t0 + p] = tile[p][c];
    }
}

// ---------------- launcher ----------------
extern "C" void kernel_launch(void* const* d_in, const int* in_sizes, int n_in,
                              void* d_out, int out_size, void* d_ws, size_t ws_size,
                              hipStream_t stream) {
    const float* x          = (const float*)d_in[0];
    const float* rots       = (const float*)d_in[1];
    const float* trans      = (const float*)d_in[2];
    const float* intrins    = (const float*)d_in[3];
    const float* post_rots  = (const float*)d_in[4];
    const float* post_trans = (const float*)d_in[5];
    const float* Wd         = (const float*)d_in[6];
    const float* bd         = (const float*)d_in[7];
    float* out = (float*)d_out;

    const size_t scat_bytes = (size_t)TOT * CT * sizeof(float);  // 16.78 MB
    float*  scat = (float*)d_ws;
    double* tf   = (double*)((char*)d_ws + scat_bytes);

    hipMemsetAsync(d_ws, 0, scat_bytes, stream);
    tf_kernel<<<1, 64, 0, stream>>>(rots, trans, intrins, post_rots, post_trans, tf);
    fused_kernel<<<B_*N_*NTILE, 256, 0, stream>>>(x, Wd, bd, tf, scat);
    transpose_k<<<B_*(NYY*NXX/64), 256, 0, stream>>>(scat, out);
}

// Round 2
// 864.529 us; speedup vs baseline: 3.7550x; 3.7550x over previous
//
#include <hip/hip_runtime.h>
#include <math.h>

#define B_   4
#define N_   6
#define CIN  512
#define CT   64
#define Dd   41
#define FH   16
#define FW   44
#define NPIX (FH*FW)      // 704
#define NO   (Dd+CT)      // 105
#define NXX  128
#define NYY  128
#define NZZ  1
#define TOT  (B_*NZZ*NYY*NXX)   // 65536
#define NPTS (B_*N_*Dd*NPIX)    // 692736

#define PIXT 32
#define NTILE (NPIX/PIXT) // 22
#define KC   32

// ---------------- helpers ----------------

__device__ __forceinline__ void inv3(const double* m, double* o) {
    double a=m[0],b=m[1],c=m[2],d=m[3],e=m[4],f=m[5],g=m[6],h=m[7],i=m[8];
    double A  =  (e*i - f*h);
    double Bc = -(d*i - f*g);
    double Cc =  (d*h - e*g);
    double det = a*A + b*Bc + c*Cc;
    double inv = 1.0/det;
    o[0]=A*inv;            o[1]=-(b*i - c*h)*inv;  o[2]= (b*f - c*e)*inv;
    o[3]=Bc*inv;           o[4]= (a*i - c*g)*inv;  o[5]=-(a*f - c*d)*inv;
    o[6]=Cc*inv;           o[7]=-(a*h - b*g)*inv;  o[8]= (a*e - b*d)*inv;
}

// geometry for one point (d, pixel) of camera bn; returns vox or -1.
__device__ __forceinline__ int point_vox(const double* tfp, int b, int d, int hh, int ww) {
    const double DXD = (double)0.8f;
    const double LOX = (double)(-50.8f) - DXD*0.5;
    const double LOY = LOX;
    const double DZD = 20.0;
    const double LOZ = -10.0;
    double fx = (double)((float)(ww * (703.0/43.0)));
    double fy = (double)((float)(hh * 17.0));
    double fz = 4.0 + (double)d;
    double px = fx - tfp[21], py = fy - tfp[22], pz = fz - tfp[23];
    double qx = tfp[ 9]*px + tfp[10]*py + tfp[11]*pz;
    double qy = tfp[12]*px + tfp[13]*py + tfp[14]*pz;
    double qz = tfp[15]*px + tfp[16]*py + tfp[17]*pz;
    double rx = qx*qz, ry = qy*qz, rz = qz;
    double sx = tfp[0]*rx + tfp[1]*ry + tfp[2]*rz + tfp[18];
    double sy = tfp[3]*rx + tfp[4]*ry + tfp[5]*rz + tfp[19];
    double sz = tfp[6]*rx + tfp[7]*ry + tfp[8]*rz + tfp[20];
    int gx = (int)((sx - LOX) / DXD);
    int gy = (int)((sy - LOY) / DXD);
    int gz = (int)((sz - LOZ) / DZD);
    bool kept = (gx>=0) & (gx<NXX) & (gy>=0) & (gy<NYY) & (gz>=0) & (gz<NZZ);
    return kept ? (((b*NZZ + gz)*NYY + gy)*NXX + gx) : -1;
}

// ---------------- kernel A: per-(b,n) transforms (double) ----------------
__global__ void tf_kernel(const float* __restrict__ rots,
                          const float* __restrict__ trans,
                          const float* __restrict__ intrins,
                          const float* __restrict__ post_rots,
                          const float* __restrict__ post_trans,
                          double* __restrict__ tf) {
    int bn = threadIdx.x;
    if (bn >= B_*N_) return;
    double k[9], pr[9], r[9], ik[9], ipr[9], c[9];
    for (int i=0;i<9;i++) { k[i]=intrins[bn*9+i]; pr[i]=post_rots[bn*9+i]; r[i]=rots[bn*9+i]; }
    inv3(k, ik);
    inv3(pr, ipr);
    for (int i=0;i<3;i++)
        for (int j=0;j<3;j++) {
            double s = 0.0;
            for (int kk=0;kk<3;kk++) s += r[i*3+kk]*ik[kk*3+j];
            c[i*3+j] = s;
        }
    double* o = tf + bn*24;
    for (int i=0;i<9;i++) o[i]   = c[i];
    for (int i=0;i<9;i++) o[9+i] = ipr[i];
    for (int i=0;i<3;i++) o[18+i] = (double)trans[bn*3+i];
    for (int i=0;i<3;i++) o[21+i] = (double)post_trans[bn*3+i];
}

// ---------------- kernel B: GEMM + softmax + geometry; emit featc, w, hist --------
__global__ __launch_bounds__(256) void feat_kernel(
    const float* __restrict__ x, const float* __restrict__ Wd,
    const float* __restrict__ bd, const double* __restrict__ tf,
    float* __restrict__ featc, float* __restrict__ w_arr,
    int* __restrict__ hist)
{
    __shared__ float  s_x[KC*PIXT];       // 4 KB
    __shared__ float  s_w[KC*128];        // 16 KB (o permuted: [k][(o&7)*16 + o>>3])
    __shared__ float  s_feat[NO*PIXT];    // 13.4 KB
    __shared__ float  s_red[8*PIXT];
    __shared__ float  s_max[PIXT];
    __shared__ float  s_inv[PIXT];
    __shared__ double s_tf[24];

    const int t    = threadIdx.x;
    const int p    = t & (PIXT-1);
    const int q    = t >> 5;             // 0..7
    const int bn   = blockIdx.x / NTILE;
    const int tile = blockIdx.x % NTILE;
    const int pix0 = tile * PIXT;
    const int b    = bn / N_;

    if (t < 24) s_tf[t] = tf[bn*24 + t];
    for (int i=t; i<KC*128; i+=256) s_w[i] = 0.0f;
    __syncthreads();

    float acc[16];
    #pragma unroll
    for (int j=0;j<16;j++) acc[j] = 0.0f;

    const float* xbn = x + (size_t)bn * CIN * NPIX + pix0;

    for (int k0 = 0; k0 < CIN; k0 += KC) {
        {
            int kk  = t >> 3;
            int pp4 = (t & 7) * 4;
            float4 v = *(const float4*)&xbn[(size_t)(k0+kk)*NPIX + pp4];
            *(float4*)&s_x[kk*PIXT + pp4] = v;
        }
        for (int idx4 = t; idx4 < (NO*KC)/4; idx4 += 256) {
            int o  = idx4 >> 3;
            int kk = (idx4 & 7) * 4;
            float4 v = *(const float4*)&Wd[o*CIN + k0 + kk];
            int off = ((o & 7) << 4) + (o >> 3);
            s_w[(kk+0)*128 + off] = v.x;
            s_w[(kk+1)*128 + off] = v.y;
            s_w[(kk+2)*128 + off] = v.z;
            s_w[(kk+3)*128 + off] = v.w;
        }
        __syncthreads();

        #pragma unroll
        for (int kk = 0; kk < KC; kk++) {
            float xv = s_x[kk*PIXT + p];
            const float4* wrow = (const float4*)&s_w[kk*128 + q*16];
            #pragma unroll
            for (int jj = 0; jj < 4; jj++) {
                float4 wv = wrow[jj];
                acc[jj*4+0] += wv.x * xv;
                acc[jj*4+1] += wv.y * xv;
                acc[jj*4+2] += wv.z * xv;
                acc[jj*4+3] += wv.w * xv;
            }
        }
        __syncthreads();
    }

    #pragma unroll
    for (int j=0;j<16;j++) {
        int o = q + 8*j;
        if (o < NO) s_feat[o*PIXT + p] = acc[j] + bd[o];
    }
    __syncthreads();

    // ---- softmax over depth rows ----
    float m = -3.0e38f;
    for (int d=q; d<Dd; d+=8) m = fmaxf(m, s_feat[d*PIXT+p]);
    s_red[q*PIXT+p] = m;
    __syncthreads();
    if (q == 0) {
        float mm = s_red[p];
        #pragma unroll
        for (int i=1;i<8;i++) mm = fmaxf(mm, s_red[i*PIXT+p]);
        s_max[p] = mm;
    }
    __syncthreads();
    {
        float mm = s_max[p];
        float ssum = 0.0f;
        for (int d=q; d<Dd; d+=8) {
            float e = expf(s_feat[d*PIXT+p] - mm);
            s_feat[d*PIXT+p] = e;
            ssum += e;
        }
        s_red[q*PIXT+p] = ssum;
    }
    __syncthreads();
    if (q == 0) {
        float s = 0.0f;
        #pragma unroll
        for (int i=0;i<8;i++) s += s_red[i*PIXT+p];
        s_inv[p] = 1.0f / s;
    }
    __syncthreads();

    // ---- write featc (cvt channels, pixel-major) ----
    {
        float4 v0, v1;
        v0.x = s_feat[(Dd+q*8+0)*PIXT+p]; v0.y = s_feat[(Dd+q*8+1)*PIXT+p];
        v0.z = s_feat[(Dd+q*8+2)*PIXT+p]; v0.w = s_feat[(Dd+q*8+3)*PIXT+p];
        v1.x = s_feat[(Dd+q*8+4)*PIXT+p]; v1.y = s_feat[(Dd+q*8+5)*PIXT+p];
        v1.z = s_feat[(Dd+q*8+6)*PIXT+p]; v1.w = s_feat[(Dd+q*8+7)*PIXT+p];
        float* dst = featc + ((size_t)(bn*NPIX + pix0 + p))*CT + q*8;
        *(float4*)dst = v0;
        *(float4*)(dst+4) = v1;
    }

    // ---- per-point weight + histogram ----
    for (int id = t; id < Dd*PIXT; id += 256) {
        int d  = id >> 5;
        int pp = id & (PIXT-1);
        int pixg = pix0 + pp;
        int hh = pixg / FW, ww = pixg % FW;
        int pt = (bn*Dd + d)*NPIX + pixg;
        w_arr[pt] = s_feat[d*PIXT+pp] * s_inv[pp];
        int vox = point_vox(s_tf, b, d, hh, ww);
        if (vox >= 0) atomicAdd(&hist[vox], 1);
    }
}

// ---------------- kernel C: exclusive scan over 65536 bins ----------------
__global__ __launch_bounds__(1024) void scan_kernel(const int* __restrict__ hist,
                                                    int* __restrict__ offs,
                                                    int* __restrict__ cursor) {
    __shared__ int s[1024];
    const int t = threadIdx.x;
    const int CHUNK = TOT / 1024;   // 64
    int base_idx = t * CHUNK;
    int sum = 0;
    int local[64];
    #pragma unroll 8
    for (int j=0;j<CHUNK;j++) { local[j] = hist[base_idx+j]; sum += local[j]; }
    s[t] = sum;
    __syncthreads();
    for (int off=1; off<1024; off<<=1) {
        int v = (t >= off) ? s[t-off] : 0;
        __syncthreads();
        s[t] += v;
        __syncthreads();
    }
    int run = (t==0) ? 0 : s[t-1];
    #pragma unroll 8
    for (int j=0;j<CHUNK;j++) {
        offs[base_idx+j]   = run;
        cursor[base_idx+j] = run;
        run += local[j];
    }
}

// ---------------- kernel D: scatter point indices ----------------
__global__ __launch_bounds__(256) void scatter_idx_kernel(
    const double* __restrict__ tf, const float* __restrict__ w_arr,
    int* __restrict__ cursor, int* __restrict__ order,
    float* __restrict__ wlist)
{
    int pt = blockIdx.x * 256 + threadIdx.x;
    if (pt >= NPTS) return;
    int bn  = pt / (Dd*NPIX);
    int rem = pt % (Dd*NPIX);
    int d   = rem / NPIX;
    int pix = rem % NPIX;
    int hh = pix / FW, ww = pix % FW;
    int b = bn / N_;
    double tfp[24];
    const double* g = tf + bn*24;
    #pragma unroll
    for (int i=0;i<24;i++) tfp[i] = g[i];
    int vox = point_vox(tfp, b, d, hh, ww);
    if (vox >= 0) {
        int pos = atomicAdd(&cursor[vox], 1);
        order[pos] = bn*NPIX + pix;
        wlist[pos] = w_arr[pt];
    }
}

// ---------------- kernel E: gather + write out[b][c][y][x] ----------------
__global__ __launch_bounds__(256) void gather_kernel(
    const int* __restrict__ offs, const int* __restrict__ cursor,
    const int* __restrict__ order, const float* __restrict__ wlist,
    const float* __restrict__ featc, float* __restrict__ out)
{
    __shared__ float rowbuf[CT*129];    // [c][x], pad 129 to dodge conflicts

    const int t = threadIdx.x;
    const int wv = t >> 6;       // wave 0..3
    const int l  = t & 63;       // lane = channel
    const int b  = blockIdx.x >> 7;
    const int y  = blockIdx.x & 127;

    for (int xi = 0; xi < 32; xi++) {
        int xx = wv*32 + xi;
        int v  = (b*NYY + y)*NXX + xx;
        int start = offs[v];
        int end   = cursor[v];
        float acc = 0.0f;
        int i = start;
        for (; i+3 < end; i+=4) {
            int   r0 = order[i],   r1 = order[i+1], r2 = order[i+2], r3 = order[i+3];
            float w0 = wlist[i],   w1 = wlist[i+1], w2 = wlist[i+2], w3 = wlist[i+3];
            acc += w0 * featc[(size_t)r0*CT + l];
            acc += w1 * featc[(size_t)r1*CT + l];
            acc += w2 * featc[(size_t)r2*CT + l];
            acc += w3 * featc[(size_t)r3*CT + l];
        }
        for (; i < end; i++) {
            acc += wlist[i] * featc[(size_t)order[i]*CT + l];
        }
        rowbuf[l*129 + xx] = acc;
    }
    __syncthreads();

    // coalesced write: out[((b*CT + c)*NYY + y)*NXX + x]
    #pragma unroll
    for (int j = 0; j < 32; j++) {
        int idx = t + j*256;
        int c = idx >> 7;
        int xx = idx & 127;
        out[(((size_t)b*CT + c)*NYY + y)*NXX + xx] = rowbuf[c*129 + xx];
    }
}

// ---------------- launcher ----------------
extern "C" void kernel_launch(void* const* d_in, const int* in_sizes, int n_in,
                              void* d_out, int out_size, void* d_ws, size_t ws_size,
                              hipStream_t stream) {
    const float* x          = (const float*)d_in[0];
    const float* rots       = (const float*)d_in[1];
    const float* trans      = (const float*)d_in[2];
    const float* intrins    = (const float*)d_in[3];
    const float* post_rots  = (const float*)d_in[4];
    const float* post_trans = (const float*)d_in[5];
    const float* Wd         = (const float*)d_in[6];
    const float* bd         = (const float*)d_in[7];
    float* out = (float*)d_out;

    char* ws = (char*)d_ws;
    float*  featc  = (float*)ws;                       ws += (size_t)B_*N_*NPIX*CT*4;   // 4.33 MB
    float*  w_arr  = (float*)ws;                       ws += (size_t)NPTS*4;            // 2.77 MB
    int*    order  = (int*)ws;                         ws += (size_t)NPTS*4;            // 2.77 MB
    float*  wlist  = (float*)ws;                       ws += (size_t)NPTS*4;            // 2.77 MB
    int*    hist   = (int*)ws;                         ws += (size_t)TOT*4;             // 0.26 MB
    int*    offs   = (int*)ws;                         ws += (size_t)TOT*4;
    int*    cursor = (int*)ws;                         ws += (size_t)TOT*4;
    double* tf     = (double*)ws;                      ws += (size_t)B_*N_*24*8;

    hipMemsetAsync(hist, 0, (size_t)TOT*4, stream);
    tf_kernel<<<1, 64, 0, stream>>>(rots, trans, intrins, post_rots, post_trans, tf);
    feat_kernel<<<B_*N_*NTILE, 256, 0, stream>>>(x, Wd, bd, tf, featc, w_arr, hist);
    scan_kernel<<<1, 1024, 0, stream>>>(hist, offs, cursor);
    scatter_idx_kernel<<<(NPTS+255)/256, 256, 0, stream>>>(tf, w_arr, cursor, order, wlist);
    gather_kernel<<<B_*NYY, 256, 0, stream>>>(offs, cursor, order, wlist, featc, out);
}

// Round 3
// 793.272 us; speedup vs baseline: 4.0923x; 1.0898x over previous
//
#include <hip/hip_runtime.h>
#include <math.h>

#define B_   4
#define N_   6
#define CIN  512
#define CT   64
#define Dd   41
#define FH   16
#define FW   44
#define NPIX (FH*FW)      // 704
#define NO   (Dd+CT)      // 105
#define NXX  128
#define NYY  128
#define NZZ  1
#define TOT  (B_*NZZ*NYY*NXX)   // 65536
#define NPTS (B_*N_*Dd*NPIX)    // 692736

#define PIXT 32
#define NTILE (NPIX/PIXT) // 22
#define KC   32

// ---------------- helpers ----------------

__device__ __forceinline__ void inv3(const double* m, double* o) {
    double a=m[0],b=m[1],c=m[2],d=m[3],e=m[4],f=m[5],g=m[6],h=m[7],i=m[8];
    double A  =  (e*i - f*h);
    double Bc = -(d*i - f*g);
    double Cc =  (d*h - e*g);
    double det = a*A + b*Bc + c*Cc;
    double inv = 1.0/det;
    o[0]=A*inv;            o[1]=-(b*i - c*h)*inv;  o[2]= (b*f - c*e)*inv;
    o[3]=Bc*inv;           o[4]= (a*i - c*g)*inv;  o[5]=-(a*f - c*d)*inv;
    o[6]=Cc*inv;           o[7]=-(a*h - b*g)*inv;  o[8]= (a*e - b*d)*inv;
}

// geometry for one point (d, pixel) of camera bn; returns vox or -1.
__device__ __forceinline__ int point_vox(const double* tfp, int b, int d, int hh, int ww) {
    const double DXD = (double)0.8f;
    const double LOX = (double)(-50.8f) - DXD*0.5;
    const double LOY = LOX;
    const double DZD = 20.0;
    const double LOZ = -10.0;
    double fx = (double)((float)(ww * (703.0/43.0)));
    double fy = (double)((float)(hh * 17.0));
    double fz = 4.0 + (double)d;
    double px = fx - tfp[21], py = fy - tfp[22], pz = fz - tfp[23];
    double qx = tfp[ 9]*px + tfp[10]*py + tfp[11]*pz;
    double qy = tfp[12]*px + tfp[13]*py + tfp[14]*pz;
    double qz = tfp[15]*px + tfp[16]*py + tfp[17]*pz;
    double rx = qx*qz, ry = qy*qz, rz = qz;
    double sx = tfp[0]*rx + tfp[1]*ry + tfp[2]*rz + tfp[18];
    double sy = tfp[3]*rx + tfp[4]*ry + tfp[5]*rz + tfp[19];
    double sz = tfp[6]*rx + tfp[7]*ry + tfp[8]*rz + tfp[20];
    int gx = (int)((sx - LOX) / DXD);
    int gy = (int)((sy - LOY) / DXD);
    int gz = (int)((sz - LOZ) / DZD);
    bool kept = (gx>=0) & (gx<NXX) & (gy>=0) & (gy<NYY) & (gz>=0) & (gz<NZZ);
    return kept ? (((b*NZZ + gz)*NYY + gy)*NXX + gx) : -1;
}

// ---------------- kernel A: per-(b,n) transforms (double) ----------------
__global__ void tf_kernel(const float* __restrict__ rots,
                          const float* __restrict__ trans,
                          const float* __restrict__ intrins,
                          const float* __restrict__ post_rots,
                          const float* __restrict__ post_trans,
                          double* __restrict__ tf) {
    int bn = threadIdx.x;
    if (bn >= B_*N_) return;
    double k[9], pr[9], r[9], ik[9], ipr[9], c[9];
    for (int i=0;i<9;i++) { k[i]=intrins[bn*9+i]; pr[i]=post_rots[bn*9+i]; r[i]=rots[bn*9+i]; }
    inv3(k, ik);
    inv3(pr, ipr);
    for (int i=0;i<3;i++)
        for (int j=0;j<3;j++) {
            double s = 0.0;
            for (int kk=0;kk<3;kk++) s += r[i*3+kk]*ik[kk*3+j];
            c[i*3+j] = s;
        }
    double* o = tf + bn*24;
    for (int i=0;i<9;i++) o[i]   = c[i];
    for (int i=0;i<9;i++) o[9+i] = ipr[i];
    for (int i=0;i<3;i++) o[18+i] = (double)trans[bn*3+i];
    for (int i=0;i<3;i++) o[21+i] = (double)post_trans[bn*3+i];
}

// ---------------- kernel B: GEMM + softmax + geometry; emit featc, w, vox, hist ----
__global__ __launch_bounds__(256) void feat_kernel(
    const float* __restrict__ x, const float* __restrict__ Wd,
    const float* __restrict__ bd, const double* __restrict__ tf,
    float* __restrict__ featc, float* __restrict__ w_arr,
    int* __restrict__ vox_arr, int* __restrict__ hist)
{
    __shared__ float  s_x[KC*PIXT];       // 4 KB
    __shared__ float  s_w[KC*128];        // 16 KB (o permuted: [k][(o&7)*16 + o>>3])
    __shared__ float  s_feat[NO*PIXT];    // 13.4 KB
    __shared__ float  s_red[8*PIXT];
    __shared__ float  s_max[PIXT];
    __shared__ float  s_inv[PIXT];
    __shared__ double s_tf[24];

    const int t    = threadIdx.x;
    const int p    = t & (PIXT-1);
    const int q    = t >> 5;             // 0..7
    const int bn   = blockIdx.x / NTILE;
    const int tile = blockIdx.x % NTILE;
    const int pix0 = tile * PIXT;
    const int b    = bn / N_;

    if (t < 24) s_tf[t] = tf[bn*24 + t];
    for (int i=t; i<KC*128; i+=256) s_w[i] = 0.0f;
    __syncthreads();

    float acc[16];
    #pragma unroll
    for (int j=0;j<16;j++) acc[j] = 0.0f;

    const float* xbn = x + (size_t)bn * CIN * NPIX + pix0;

    for (int k0 = 0; k0 < CIN; k0 += KC) {
        {
            int kk  = t >> 3;
            int pp4 = (t & 7) * 4;
            float4 v = *(const float4*)&xbn[(size_t)(k0+kk)*NPIX + pp4];
            *(float4*)&s_x[kk*PIXT + pp4] = v;
        }
        for (int idx4 = t; idx4 < (NO*KC)/4; idx4 += 256) {
            int o  = idx4 >> 3;
            int kk = (idx4 & 7) * 4;
            float4 v = *(const float4*)&Wd[o*CIN + k0 + kk];
            int off = ((o & 7) << 4) + (o >> 3);
            s_w[(kk+0)*128 + off] = v.x;
            s_w[(kk+1)*128 + off] = v.y;
            s_w[(kk+2)*128 + off] = v.z;
            s_w[(kk+3)*128 + off] = v.w;
        }
        __syncthreads();

        #pragma unroll
        for (int kk = 0; kk < KC; kk++) {
            float xv = s_x[kk*PIXT + p];
            const float4* wrow = (const float4*)&s_w[kk*128 + q*16];
            #pragma unroll
            for (int jj = 0; jj < 4; jj++) {
                float4 wv = wrow[jj];
                acc[jj*4+0] += wv.x * xv;
                acc[jj*4+1] += wv.y * xv;
                acc[jj*4+2] += wv.z * xv;
                acc[jj*4+3] += wv.w * xv;
            }
        }
        __syncthreads();
    }

    #pragma unroll
    for (int j=0;j<16;j++) {
        int o = q + 8*j;
        if (o < NO) s_feat[o*PIXT + p] = acc[j] + bd[o];
    }
    __syncthreads();

    // ---- softmax over depth rows ----
    float m = -3.0e38f;
    for (int d=q; d<Dd; d+=8) m = fmaxf(m, s_feat[d*PIXT+p]);
    s_red[q*PIXT+p] = m;
    __syncthreads();
    if (q == 0) {
        float mm = s_red[p];
        #pragma unroll
        for (int i=1;i<8;i++) mm = fmaxf(mm, s_red[i*PIXT+p]);
        s_max[p] = mm;
    }
    __syncthreads();
    {
        float mm = s_max[p];
        float ssum = 0.0f;
        for (int d=q; d<Dd; d+=8) {
            float e = expf(s_feat[d*PIXT+p] - mm);
            s_feat[d*PIXT+p] = e;
            ssum += e;
        }
        s_red[q*PIXT+p] = ssum;
    }
    __syncthreads();
    if (q == 0) {
        float s = 0.0f;
        #pragma unroll
        for (int i=0;i<8;i++) s += s_red[i*PIXT+p];
        s_inv[p] = 1.0f / s;
    }
    __syncthreads();

    // ---- write featc (cvt channels, pixel-major) ----
    {
        float4 v0, v1;
        v0.x = s_feat[(Dd+q*8+0)*PIXT+p]; v0.y = s_feat[(Dd+q*8+1)*PIXT+p];
        v0.z = s_feat[(Dd+q*8+2)*PIXT+p]; v0.w = s_feat[(Dd+q*8+3)*PIXT+p];
        v1.x = s_feat[(Dd+q*8+4)*PIXT+p]; v1.y = s_feat[(Dd+q*8+5)*PIXT+p];
        v1.z = s_feat[(Dd+q*8+6)*PIXT+p]; v1.w = s_feat[(Dd+q*8+7)*PIXT+p];
        float* dst = featc + ((size_t)(bn*NPIX + pix0 + p))*CT + q*8;
        *(float4*)dst = v0;
        *(float4*)(dst+4) = v1;
    }

    // ---- per-point weight + voxel id + histogram ----
    for (int id = t; id < Dd*PIXT; id += 256) {
        int d  = id >> 5;
        int pp = id & (PIXT-1);
        int pixg = pix0 + pp;
        int hh = pixg / FW, ww = pixg % FW;
        int pt = (bn*Dd + d)*NPIX + pixg;
        w_arr[pt] = s_feat[d*PIXT+pp] * s_inv[pp];
        int vox = point_vox(s_tf, b, d, hh, ww);
        vox_arr[pt] = vox;
        if (vox >= 0) atomicAdd(&hist[vox], 1);
    }
}

// ---------------- kernel C: exclusive scan over 65536 bins ----------------
__global__ __launch_bounds__(1024) void scan_kernel(const int* __restrict__ hist,
                                                    int* __restrict__ offs,
                                                    int* __restrict__ cursor) {
    __shared__ int s[1024];
    const int t = threadIdx.x;
    const int CHUNK = TOT / 1024;   // 64
    int base_idx = t * CHUNK;
    int sum = 0;
    int local[64];
    #pragma unroll 8
    for (int j=0;j<CHUNK;j++) { local[j] = hist[base_idx+j]; sum += local[j]; }
    s[t] = sum;
    __syncthreads();
    for (int off=1; off<1024; off<<=1) {
        int v = (t >= off) ? s[t-off] : 0;
        __syncthreads();
        s[t] += v;
        __syncthreads();
    }
    int run = (t==0) ? 0 : s[t-1];
    #pragma unroll 8
    for (int j=0;j<CHUNK;j++) {
        offs[base_idx+j]   = run;
        cursor[base_idx+j] = run;
        run += local[j];
    }
}

// ---------------- kernel D: scatter point indices (vox precomputed) ----------------
__global__ __launch_bounds__(256) void scatter_idx_kernel(
    const int* __restrict__ vox_arr, const float* __restrict__ w_arr,
    int* __restrict__ cursor, int* __restrict__ order,
    float* __restrict__ wlist)
{
    int pt = blockIdx.x * 256 + threadIdx.x;
    if (pt >= NPTS) return;
    int vox = vox_arr[pt];
    if (vox >= 0) {
        int bn  = pt / (Dd*NPIX);
        int pix = pt % NPIX;
        int pos = atomicAdd(&cursor[vox], 1);
        order[pos] = bn*NPIX + pix;
        wlist[pos] = w_arr[pt];
    }
}

// ---------------- kernel E: gather + write out[b][c][y][x] ----------------
// grid = B*NYY*4 blocks; block covers 32 x-cells of row (b,y); wave per voxel.
__global__ __launch_bounds__(256) void gather_kernel(
    const int* __restrict__ offs, const int* __restrict__ cursor,
    const int* __restrict__ order, const float* __restrict__ wlist,
    const float* __restrict__ featc, float* __restrict__ out)
{
    __shared__ float rowbuf[CT*33];   // [c][xx], stride 33

    const int t  = threadIdx.x;
    const int wv = t >> 6;       // wave 0..3
    const int l  = t & 63;       // lane = channel
    const int by = blockIdx.x >> 2;
    const int x0 = (blockIdx.x & 3) * 32;
    const int b  = by >> 7;
    const int y  = by & 127;

    #pragma unroll
    for (int xi = 0; xi < 8; xi++) {
        int xx = wv*8 + xi;                       // 0..31
        int v  = (b*NYY + y)*NXX + x0 + xx;
        int start = offs[v];
        int end   = cursor[v];
        float acc = 0.0f;
        for (int base = start; base < end; base += 64) {
            int  navail = end - base;
            int  ordv = 0; float wval = 0.0f;
            if (l < navail) { ordv = order[base + l]; wval = wlist[base + l]; }
            int cnt = navail < 64 ? navail : 64;
            #pragma unroll 4
            for (int j = 0; j < cnt; j++) {
                int   r = __shfl(ordv, j);
                float w = __shfl(wval, j);
                acc += w * featc[(size_t)r*CT + l];
            }
        }
        rowbuf[l*33 + xx] = acc;
    }
    __syncthreads();

    // coalesced write: out[((b*CT + c)*NYY + y)*NXX + x0 + xx]
    #pragma unroll
    for (int j = 0; j < 8; j++) {
        int idx = t + j*256;
        int c  = idx >> 5;
        int xx = idx & 31;
        out[(((size_t)b*CT + c)*NYY + y)*NXX + x0 + xx] = rowbuf[c*33 + xx];
    }
}

// ---------------- launcher ----------------
extern "C" void kernel_launch(void* const* d_in, const int* in_sizes, int n_in,
                              void* d_out, int out_size, void* d_ws, size_t ws_size,
                              hipStream_t stream) {
    const float* x          = (const float*)d_in[0];
    const float* rots       = (const float*)d_in[1];
    const float* trans      = (const float*)d_in[2];
    const float* intrins    = (const float*)d_in[3];
    const float* post_rots  = (const float*)d_in[4];
    const float* post_trans = (const float*)d_in[5];
    const float* Wd         = (const float*)d_in[6];
    const float* bd         = (const float*)d_in[7];
    float* out = (float*)d_out;

    char* ws = (char*)d_ws;
    float*  featc   = (float*)ws;                      ws += (size_t)B_*N_*NPIX*CT*4;   // 4.33 MB
    float*  w_arr   = (float*)ws;                      ws += (size_t)NPTS*4;            // 2.77 MB
    int*    vox_arr = (int*)ws;                        ws += (size_t)NPTS*4;            // 2.77 MB
    int*    order   = (int*)ws;                        ws += (size_t)NPTS*4;            // 2.77 MB
    float*  wlist   = (float*)ws;                      ws += (size_t)NPTS*4;            // 2.77 MB
    int*    hist    = (int*)ws;                        ws += (size_t)TOT*4;             // 0.26 MB
    int*    offs    = (int*)ws;                        ws += (size_t)TOT*4;
    int*    cursor  = (int*)ws;                        ws += (size_t)TOT*4;
    double* tf      = (double*)ws;                     ws += (size_t)B_*N_*24*8;

    hipMemsetAsync(hist, 0, (size_t)TOT*4, stream);
    tf_kernel<<<1, 64, 0, stream>>>(rots, trans, intrins, post_rots, post_trans, tf);
    feat_kernel<<<B_*N_*NTILE, 256, 0, stream>>>(x, Wd, bd, tf, featc, w_arr, vox_arr, hist);
    scan_kernel<<<1, 1024, 0, stream>>>(hist, offs, cursor);
    scatter_idx_kernel<<<(NPTS+255)/256, 256, 0, stream>>>(vox_arr, w_arr, cursor, order, wlist);
    gather_kernel<<<B_*NYY*4, 256, 0, stream>>>(offs, cursor, order, wlist, featc, out);
}

// Round 4
// 462.104 us; speedup vs baseline: 7.0251x; 1.7167x over previous
//
#include <hip/hip_runtime.h>
#include <math.h>

#define B_   4
#define N_   6
#define CIN  512
#define CT   64
#define Dd   41
#define FH   16
#define FW   44
#define NPIX (FH*FW)      // 704
#define NO   (Dd+CT)      // 105
#define NXX  128
#define NYY  128
#define NZZ  1
#define TOT  (B_*NZZ*NYY*NXX)   // 65536
#define NPTS (B_*N_*Dd*NPIX)    // 692736
#define NCHUNK ((NPTS+63)/64)   // 10824

#define PIXT 32
#define NTILE (NPIX/PIXT) // 22
#define KC   32

#define PK_INVALID 0xFFFFFFFFu

// ---------------- helpers ----------------

__device__ __forceinline__ void inv3(const double* m, double* o) {
    double a=m[0],b=m[1],c=m[2],d=m[3],e=m[4],f=m[5],g=m[6],h=m[7],i=m[8];
    double A  =  (e*i - f*h);
    double Bc = -(d*i - f*g);
    double Cc =  (d*h - e*g);
    double det = a*A + b*Bc + c*Cc;
    double inv = 1.0/det;
    o[0]=A*inv;            o[1]=-(b*i - c*h)*inv;  o[2]= (b*f - c*e)*inv;
    o[3]=Bc*inv;           o[4]= (a*i - c*g)*inv;  o[5]=-(a*f - c*d)*inv;
    o[6]=Cc*inv;           o[7]=-(a*h - b*g)*inv;  o[8]= (a*e - b*d)*inv;
}

// geometry for one point (d, pixel) of camera bn; returns vox or -1.
__device__ __forceinline__ int point_vox(const double* tfp, int b, int d, int hh, int ww) {
    const double DXD = (double)0.8f;
    const double LOX = (double)(-50.8f) - DXD*0.5;
    const double LOY = LOX;
    const double DZD = 20.0;
    const double LOZ = -10.0;
    double fx = (double)((float)(ww * (703.0/43.0)));
    double fy = (double)((float)(hh * 17.0));
    double fz = 4.0 + (double)d;
    double px = fx - tfp[21], py = fy - tfp[22], pz = fz - tfp[23];
    double qx = tfp[ 9]*px + tfp[10]*py + tfp[11]*pz;
    double qy = tfp[12]*px + tfp[13]*py + tfp[14]*pz;
    double qz = tfp[15]*px + tfp[16]*py + tfp[17]*pz;
    double rx = qx*qz, ry = qy*qz, rz = qz;
    double sx = tfp[0]*rx + tfp[1]*ry + tfp[2]*rz + tfp[18];
    double sy = tfp[3]*rx + tfp[4]*ry + tfp[5]*rz + tfp[19];
    double sz = tfp[6]*rx + tfp[7]*ry + tfp[8]*rz + tfp[20];
    int gx = (int)((sx - LOX) / DXD);
    int gy = (int)((sy - LOY) / DXD);
    int gz = (int)((sz - LOZ) / DZD);
    bool kept = (gx>=0) & (gx<NXX) & (gy>=0) & (gy<NYY) & (gz>=0) & (gz<NZZ);
    return kept ? (((b*NZZ + gz)*NYY + gy)*NXX + gx) : -1;
}

// ---------------- kernel A: per-(b,n) transforms (double) ----------------
__global__ void tf_kernel(const float* __restrict__ rots,
                          const float* __restrict__ trans,
                          const float* __restrict__ intrins,
                          const float* __restrict__ post_rots,
                          const float* __restrict__ post_trans,
                          double* __restrict__ tf) {
    int bn = threadIdx.x;
    if (bn >= B_*N_) return;
    double k[9], pr[9], r[9], ik[9], ipr[9], c[9];
    for (int i=0;i<9;i++) { k[i]=intrins[bn*9+i]; pr[i]=post_rots[bn*9+i]; r[i]=rots[bn*9+i]; }
    inv3(k, ik);
    inv3(pr, ipr);
    for (int i=0;i<3;i++)
        for (int j=0;j<3;j++) {
            double s = 0.0;
            for (int kk=0;kk<3;kk++) s += r[i*3+kk]*ik[kk*3+j];
            c[i*3+j] = s;
        }
    double* o = tf + bn*24;
    for (int i=0;i<9;i++) o[i]   = c[i];
    for (int i=0;i<9;i++) o[9+i] = ipr[i];
    for (int i=0;i<3;i++) o[18+i] = (double)trans[bn*3+i];
    for (int i=0;i<3;i++) o[21+i] = (double)post_trans[bn*3+i];
}

// ---------------- kernel B: GEMM + softmax + geometry; emit featc, pk, w, hist ----
__global__ __launch_bounds__(256) void feat_kernel(
    const float* __restrict__ x, const float* __restrict__ Wd,
    const float* __restrict__ bd, const double* __restrict__ tf,
    float* __restrict__ featc, unsigned* __restrict__ pk_arr,
    float* __restrict__ w_arr, int* __restrict__ hist)
{
    __shared__ float  s_x[KC*PIXT];       // 4 KB
    __shared__ float  s_w[KC*128];        // 16 KB (o permuted: [k][(o&7)*16 + o>>3])
    __shared__ float  s_feat[NO*PIXT];    // 13.4 KB
    __shared__ float  s_red[8*PIXT];
    __shared__ float  s_max[PIXT];
    __shared__ float  s_inv[PIXT];
    __shared__ double s_tf[24];

    const int t    = threadIdx.x;
    const int p    = t & (PIXT-1);
    const int q    = t >> 5;             // 0..7
    const int bn   = blockIdx.x / NTILE;
    const int tile = blockIdx.x % NTILE;
    const int pix0 = tile * PIXT;
    const int b    = bn / N_;

    if (t < 24) s_tf[t] = tf[bn*24 + t];
    for (int i=t; i<KC*128; i+=256) s_w[i] = 0.0f;
    __syncthreads();

    float acc[16];
    #pragma unroll
    for (int j=0;j<16;j++) acc[j] = 0.0f;

    const float* xbn = x + (size_t)bn * CIN * NPIX + pix0;

    for (int k0 = 0; k0 < CIN; k0 += KC) {
        {
            int kk  = t >> 3;
            int pp4 = (t & 7) * 4;
            float4 v = *(const float4*)&xbn[(size_t)(k0+kk)*NPIX + pp4];
            *(float4*)&s_x[kk*PIXT + pp4] = v;
        }
        for (int idx4 = t; idx4 < (NO*KC)/4; idx4 += 256) {
            int o  = idx4 >> 3;
            int kk = (idx4 & 7) * 4;
            float4 v = *(const float4*)&Wd[o*CIN + k0 + kk];
            int off = ((o & 7) << 4) + (o >> 3);
            s_w[(kk+0)*128 + off] = v.x;
            s_w[(kk+1)*128 + off] = v.y;
            s_w[(kk+2)*128 + off] = v.z;
            s_w[(kk+3)*128 + off] = v.w;
        }
        __syncthreads();

        #pragma unroll
        for (int kk = 0; kk < KC; kk++) {
            float xv = s_x[kk*PIXT + p];
            const float4* wrow = (const float4*)&s_w[kk*128 + q*16];
            #pragma unroll
            for (int jj = 0; jj < 4; jj++) {
                float4 wv = wrow[jj];
                acc[jj*4+0] += wv.x * xv;
                acc[jj*4+1] += wv.y * xv;
                acc[jj*4+2] += wv.z * xv;
                acc[jj*4+3] += wv.w * xv;
            }
        }
        __syncthreads();
    }

    #pragma unroll
    for (int j=0;j<16;j++) {
        int o = q + 8*j;
        if (o < NO) s_feat[o*PIXT + p] = acc[j] + bd[o];
    }
    __syncthreads();

    // ---- softmax over depth rows ----
    float m = -3.0e38f;
    for (int d=q; d<Dd; d+=8) m = fmaxf(m, s_feat[d*PIXT+p]);
    s_red[q*PIXT+p] = m;
    __syncthreads();
    if (q == 0) {
        float mm = s_red[p];
        #pragma unroll
        for (int i=1;i<8;i++) mm = fmaxf(mm, s_red[i*PIXT+p]);
        s_max[p] = mm;
    }
    __syncthreads();
    {
        float mm = s_max[p];
        float ssum = 0.0f;
        for (int d=q; d<Dd; d+=8) {
            float e = expf(s_feat[d*PIXT+p] - mm);
            s_feat[d*PIXT+p] = e;
            ssum += e;
        }
        s_red[q*PIXT+p] = ssum;
    }
    __syncthreads();
    if (q == 0) {
        float s = 0.0f;
        #pragma unroll
        for (int i=0;i<8;i++) s += s_red[i*PIXT+p];
        s_inv[p] = 1.0f / s;
    }
    __syncthreads();

    // ---- write featc (cvt channels, pixel-major) ----
    {
        float4 v0, v1;
        v0.x = s_feat[(Dd+q*8+0)*PIXT+p]; v0.y = s_feat[(Dd+q*8+1)*PIXT+p];
        v0.z = s_feat[(Dd+q*8+2)*PIXT+p]; v0.w = s_feat[(Dd+q*8+3)*PIXT+p];
        v1.x = s_feat[(Dd+q*8+4)*PIXT+p]; v1.y = s_feat[(Dd+q*8+5)*PIXT+p];
        v1.z = s_feat[(Dd+q*8+6)*PIXT+p]; v1.w = s_feat[(Dd+q*8+7)*PIXT+p];
        float* dst = featc + ((size_t)(bn*NPIX + pix0 + p))*CT + q*8;
        *(float4*)dst = v0;
        *(float4*)(dst+4) = v1;
    }

    // ---- per-point weight + packed (vox,id) + histogram ----
    for (int id = t; id < Dd*PIXT; id += 256) {
        int d  = id >> 5;
        int pp = id & (PIXT-1);
        int pixg = pix0 + pp;
        int hh = pixg / FW, ww = pixg % FW;
        int pt = (bn*Dd + d)*NPIX + pixg;
        w_arr[pt] = s_feat[d*PIXT+pp] * s_inv[pp];
        int vox = point_vox(s_tf, b, d, hh, ww);
        unsigned pix_id = (unsigned)(bn*NPIX + pixg);          // < 2^15
        pk_arr[pt] = (vox >= 0) ? (((unsigned)vox << 15) | pix_id) : PK_INVALID;
        if (vox >= 0) atomicAdd(&hist[vox], 1);
    }
}

// ---------------- kernel C: exclusive scan over 65536 bins -> cursor ----------------
__global__ __launch_bounds__(1024) void scan_kernel(const int* __restrict__ hist,
                                                    int* __restrict__ cursor) {
    __shared__ int s[1024];
    const int t = threadIdx.x;
    const int CHUNK = TOT / 1024;   // 64
    int base_idx = t * CHUNK;
    int sum = 0;
    int local[64];
    #pragma unroll 8
    for (int j=0;j<CHUNK;j++) { local[j] = hist[base_idx+j]; sum += local[j]; }
    s[t] = sum;
    __syncthreads();
    for (int off=1; off<1024; off<<=1) {
        int v = (t >= off) ? s[t-off] : 0;
        __syncthreads();
        s[t] += v;
        __syncthreads();
    }
    int run = (t==0) ? 0 : s[t-1];
    #pragma unroll 8
    for (int j=0;j<CHUNK;j++) {
        cursor[base_idx+j] = run;
        run += local[j];
    }
}

// ---------------- kernel D: scatter packed records into sorted order ----------------
__global__ __launch_bounds__(256) void scatter_idx_kernel(
    const unsigned* __restrict__ pk_arr, const float* __restrict__ w_arr,
    int* __restrict__ cursor, unsigned* __restrict__ spk,
    float* __restrict__ sw)
{
    int pt = blockIdx.x * 256 + threadIdx.x;
    if (pt >= NPTS) return;
    unsigned pk = pk_arr[pt];
    if (pk != PK_INVALID) {
        int v = pk >> 15;
        int pos = atomicAdd(&cursor[v], 1);
        spk[pos] = pk;
        sw[pos]  = w_arr[pt];
    }
}

// ---------------- kernel E: balanced segmented gather -> scat[vox][ct] ----------------
// One wave per 64-point chunk of the sorted array. Runs (same-voxel spans) found
// via ballot; interior runs -> exclusive plain store, edge runs -> atomic add.
__global__ __launch_bounds__(256) void gather_kernel(
    const unsigned* __restrict__ spk, const float* __restrict__ sw,
    const int* __restrict__ cursor, const float* __restrict__ featc,
    float* __restrict__ scat)
{
    const int t  = threadIdx.x;
    const int wv = t >> 6;
    const int l  = t & 63;
    const int chunk = blockIdx.x * 4 + wv;
    const int base  = chunk * 64;
    const int Np = cursor[TOT-1];          // total valid points
    if (base >= Np) return;
    int cnt = Np - base; if (cnt > 64) cnt = 64;

    unsigned pk = 0; float w = 0.0f;
    if (l < cnt) { pk = spk[base + l]; w = sw[base + l]; }
    unsigned pkm = __shfl(pk, (l == 0) ? 0 : (l - 1));
    unsigned long long starts =
        __ballot((l > 0) && (l < cnt) && ((pk >> 15) != (pkm >> 15)));

    unsigned long long m = starts;
    int rs = 0;
    while (rs < cnt) {
        int re = m ? (__ffsll((unsigned long long)m) - 1) : cnt;
        if (m) m &= m - 1;
        float acc = 0.0f;
        for (int j = rs; j < re; j++) {
            unsigned pkj = __shfl(pk, j);
            float    wj  = __shfl(w, j);
            unsigned id  = pkj & 0x7FFFu;
            acc += wj * featc[(size_t)id * CT + l];
        }
        unsigned vrun = __shfl(pk, rs) >> 15;
        float* dst = scat + (size_t)vrun * CT + l;
        if (rs == 0 || re == cnt) {
            unsafeAtomicAdd(dst, acc);      // run may continue in adjacent chunk
        } else {
            *dst = acc;                     // voxel wholly owned by this chunk
        }
        rs = re;
    }
}

// ---------------- kernel F: transpose (b,pix,ct) -> (b,ct,pix) ----------------
__global__ __launch_bounds__(256) void transpose_k(const float* __restrict__ scat,
                                                   float* __restrict__ out) {
    __shared__ float tile[64][65];
    int b  = blockIdx.x >> 8;
    int t0 = (blockIdx.x & 255) * 64;
    const float* src = scat + (size_t)b * (NYY*NXX) * CT;
    #pragma unroll
    for (int i=0;i<16;i++) {
        int idx = threadIdx.x + i*256;
        int p = idx >> 6, c = idx & 63;
        tile[p][c] = src[(size_t)(t0+p)*CT + c];
    }
    __syncthreads();
    float* dst = out + (size_t)b * CT * (NYY*NXX);
    #pragma unroll
    for (int i=0;i<16;i++) {
        int idx = threadIdx.x + i*256;
        int c = idx >> 6, p = idx & 63;
        dst[(size_t)c*(NYY*NXX) + t0 + p] = tile[p][c];
    }
}

// ---------------- launcher ----------------
extern "C" void kernel_launch(void* const* d_in, const int* in_sizes, int n_in,
                              void* d_out, int out_size, void* d_ws, size_t ws_size,
                              hipStream_t stream) {
    const float* x          = (const float*)d_in[0];
    const float* rots       = (const float*)d_in[1];
    const float* trans      = (const float*)d_in[2];
    const float* intrins    = (const float*)d_in[3];
    const float* post_rots  = (const float*)d_in[4];
    const float* post_trans = (const float*)d_in[5];
    const float* Wd         = (const float*)d_in[6];
    const float* bd         = (const float*)d_in[7];
    float* out = (float*)d_out;

    char* ws = (char*)d_ws;
    float*    featc  = (float*)ws;     ws += (size_t)B_*N_*NPIX*CT*4;   // 4.33 MB
    unsigned* pk_arr = (unsigned*)ws;  ws += (size_t)NPTS*4;            // 2.77 MB
    float*    w_arr  = (float*)ws;     ws += (size_t)NPTS*4;            // 2.77 MB
    unsigned* spk    = (unsigned*)ws;  ws += (size_t)NPTS*4;            // 2.77 MB
    float*    sw     = (float*)ws;     ws += (size_t)NPTS*4;            // 2.77 MB
    float*    scat   = (float*)ws;     ws += (size_t)TOT*CT*4;          // 16.78 MB
    int*      hist   = (int*)ws;       ws += (size_t)TOT*4;             // 0.26 MB
    int*      cursor = (int*)ws;       ws += (size_t)TOT*4;             // 0.26 MB
    double*   tf     = (double*)ws;    ws += (size_t)B_*N_*24*8;

    hipMemsetAsync(scat, 0, (size_t)TOT*CT*4, stream);
    hipMemsetAsync(hist, 0, (size_t)TOT*4, stream);
    tf_kernel<<<1, 64, 0, stream>>>(rots, trans, intrins, post_rots, post_trans, tf);
    feat_kernel<<<B_*N_*NTILE, 256, 0, stream>>>(x, Wd, bd, tf, featc, pk_arr, w_arr, hist);
    scan_kernel<<<1, 1024, 0, stream>>>(hist, cursor);
    scatter_idx_kernel<<<(NPTS+255)/256, 256, 0, stream>>>(pk_arr, w_arr, cursor, spk, sw);
    gather_kernel<<<(NCHUNK+3)/4, 256, 0, stream>>>(spk, sw, cursor, featc, scat);
    transpose_k<<<B_*(NYY*NXX/64), 256, 0, stream>>>(scat, out);
}